// Round 10
// baseline (188.553 us; speedup 1.0000x reference)
//
#include <hip/hip_runtime.h>

typedef __attribute__((ext_vector_type(8))) short short8;
typedef __attribute__((ext_vector_type(4))) float floatx4;

#define D_NODE 64
#define D_OUT  64

static __device__ __forceinline__ unsigned short f2bf(float x) {
    unsigned int u = __float_as_uint(x);
    unsigned int r = u + 0x7FFFu + ((u >> 16) & 1u);
    return (unsigned short)(r >> 16);
}

static __device__ __forceinline__ short8 cvt2(floatx4 x, floatx4 y) {
    short8 a;
    a[0] = (short)f2bf(x[0]); a[1] = (short)f2bf(x[1]);
    a[2] = (short)f2bf(x[2]); a[3] = (short)f2bf(x[3]);
    a[4] = (short)f2bf(y[0]); a[5] = (short)f2bf(y[1]);
    a[6] = (short)f2bf(y[2]); a[7] = (short)f2bf(y[3]);
    return a;
}

static __device__ __forceinline__ short8 load_cvt(const float* __restrict__ p) {
    return cvt2(*(const floatx4*)p, *(const floatx4*)(p + 4));
}

static __device__ __forceinline__ floatx4 ntload4(const float* __restrict__ p) {
    return __builtin_nontemporal_load((const floatx4*)p);
}

// Permuted W packing (R3): lane owns 16 contiguous out cols.
__global__ void pack2_kernel(const float* __restrict__ W, const float* __restrict__ b,
                             const float* __restrict__ g,
                             unsigned short* __restrict__ wpe,
                             unsigned short* __restrict__ wpn,
                             float* __restrict__ gc) {
    int tid = blockIdx.x * 256 + threadIdx.x;
    if (tid < 512) {
        int lane = tid & 63;
        int ct = (tid >> 6) & 3;
        int kstep = tid >> 8;
        int kbase = kstep * 32 + (lane >> 4) * 8;
        int col = 4 * (lane & 15) + ct;
        short8 sv;
#pragma unroll
        for (int j = 0; j < 8; ++j)
            sv[j] = (short)f2bf(W[(size_t)(kbase + j) * D_OUT + col]);
        *(short8*)(wpe + (size_t)tid * 8) = sv;
    } else if (tid < 512 + 1024) {
        int t = tid - 512;
        int lane = t & 63;
        int ct = (t >> 6) & 7;
        int kstep = t >> 9;
        int kk = kstep * 32 + (lane >> 4) * 8;
        int seg = (ct < 4) ? 64 : 128;
        int col = 4 * (lane & 15) + (ct & 3);
        short8 sv;
#pragma unroll
        for (int j = 0; j < 8; ++j)
            sv[j] = (short)f2bf(W[(size_t)(seg + kk + j) * D_OUT + col]);
        *(short8*)(wpn + (size_t)t * 8) = sv;
    } else if (tid < 512 + 1024 + 64) {
        int col = tid - 1536;
        float acc = b[col];
#pragma unroll
        for (int k = 0; k < 32; ++k)
            acc += g[k] * W[(size_t)(192 + k) * D_OUT + col];
        gc[col] = acc;
    }
}

// NC (bf16): NC[i][0:64] = nodes[i]@W[64:128], NC[i][64:128] = nodes[i]@W[128:192]
__global__ __launch_bounds__(256) void node3_kernel(
    const float* __restrict__ nodes, const unsigned short* __restrict__ wpn,
    unsigned short* __restrict__ NCb, int Nn) {
    const int lane = threadIdx.x & 63;
    const int wave = threadIdx.x >> 6;
    const int g = lane >> 4;
    int nbase = blockIdx.x * 64 + wave * 16;
    if (nbase >= Nn) return;

    int na = nbase + (lane & 15);
    bool valid = na < Nn;
    if (!valid) na = Nn - 1;
    const float* pn = nodes + (size_t)na * D_NODE + g * 8;
    short8 N0 = load_cvt(pn);
    short8 N1 = load_cvt(pn + 32);

    floatx4 acc[8];
#pragma unroll
    for (int ct = 0; ct < 8; ++ct) {
        short8 B0 = *(const short8*)(wpn + ((size_t)ct * 64 + lane) * 8);
        short8 B1 = *(const short8*)(wpn + ((size_t)(8 + ct) * 64 + lane) * 8);
        acc[ct] = (floatx4){0.f, 0.f, 0.f, 0.f};
        acc[ct] = __builtin_amdgcn_mfma_f32_16x16x32_bf16(B0, N0, acc[ct], 0, 0, 0);
        acc[ct] = __builtin_amdgcn_mfma_f32_16x16x32_bf16(B1, N1, acc[ct], 0, 0, 0);
    }
    if (valid) {
        unsigned short* pr = NCb + (size_t)na * 128 + 16 * g;
#pragma unroll
        for (int j = 0; j < 4; ++j) {
            unsigned short rv[4], sv[4];
#pragma unroll
            for (int ct = 0; ct < 4; ++ct) { rv[ct] = f2bf(acc[ct][j]); sv[ct] = f2bf(acc[4 + ct][j]); }
            *(uint2*)(pr + 4 * j) = *(uint2*)rv;
            *(uint2*)(pr + 64 + 4 * j) = *(uint2*)sv;
        }
    }
}

struct EdgeRegs { floatx4 v0, v1, v2, v3; };
struct GathRegs { uint2 r0, r1, r2, r3, s0, s1, s2, s3; };
struct IdxRegs  { int r0, r1, r2, r3, s0, s1, s2, s3; };

// edge10: R9 structure, gather leg deepened to 3 tiles in flight
//   (gathers for k,k+1,k+2 resident; issue k+3 at iter k; idx 4 ahead).
//   Edges stay 2-deep (streaming, predictable); LDS double-buffered.
__global__ __launch_bounds__(256) void edge10_kernel(
    const float* __restrict__ edges,
    const int* __restrict__ recv, const int* __restrict__ send,
    const unsigned short* __restrict__ wpe, const unsigned short* __restrict__ NCb,
    const float* __restrict__ gc, float* __restrict__ out, int E, int T) {

    __shared__ char lds[4][2][4096];   // 2 regions per wave (double buffer)

    const int lane = threadIdx.x & 63;
    const int wave = threadIdx.x >> 6;
    const int g = lane >> 4;     // MFMA k-group
    const int e16 = lane & 15;   // MFMA edge-row within tile
    const int c = lane & 15;     // stream 16B chunk id (out cols [4c,4c+4))
    const int lr = lane >> 4;    // stream row-subindex
    const int stride = gridDim.x;
    const int t0 = blockIdx.x;

    short8 Bf[8];
#pragma unroll
    for (int fi = 0; fi < 8; ++fi)
        Bf[fi] = *(const short8*)(wpe + ((size_t)fi * 64 + lane) * 8);

    const floatx4 gc4 = *(const floatx4*)(gc + 4 * c);

#define TBASE(k) ((t0 + (k) * stride) * 64 + wave * 16)

    auto load_idx = [&](int b) {
        IdxRegs I;
        int q0 = b + 0 + lr;  q0 = (q0 < E) ? q0 : E - 1;
        int q1 = b + 4 + lr;  q1 = (q1 < E) ? q1 : E - 1;
        int q2 = b + 8 + lr;  q2 = (q2 < E) ? q2 : E - 1;
        int q3 = b + 12 + lr; q3 = (q3 < E) ? q3 : E - 1;
        I.r0 = recv[q0]; I.r1 = recv[q1]; I.r2 = recv[q2]; I.r3 = recv[q3];
        I.s0 = send[q0]; I.s1 = send[q1]; I.s2 = send[q2]; I.s3 = send[q3];
        return I;
    };
    // Stream-layout edge loads: instr i covers 4 rows x 256B = 16 FULL lines.
    auto load_edges = [&](int b) {
        EdgeRegs Er;
#pragma unroll
        for (int i = 0; i < 4; ++i) {
            int ci = i * 64 + lane;
            int row = b + (ci >> 4);
            row = (row < E) ? row : E - 1;
            int gch = (ci & 15) ^ ((ci >> 4) & 7);
            const float* p = edges + (size_t)row * D_NODE + gch * 4;
            floatx4 v = ntload4(p);
            if (i == 0) Er.v0 = v; else if (i == 1) Er.v1 = v;
            else if (i == 2) Er.v2 = v; else Er.v3 = v;
        }
        return Er;
    };
    auto stage_edges = [&](char* buf, const EdgeRegs& Er) {
        *(floatx4*)(buf + (0 * 64 + lane) * 16) = Er.v0;
        *(floatx4*)(buf + (1 * 64 + lane) * 16) = Er.v1;
        *(floatx4*)(buf + (2 * 64 + lane) * 16) = Er.v2;
        *(floatx4*)(buf + (3 * 64 + lane) * 16) = Er.v3;
    };
    auto load_gath = [&](const IdxRegs& I) {
        GathRegs G;
        G.r0 = *(const uint2*)(NCb + (size_t)I.r0 * 128 + 4 * c);
        G.r1 = *(const uint2*)(NCb + (size_t)I.r1 * 128 + 4 * c);
        G.r2 = *(const uint2*)(NCb + (size_t)I.r2 * 128 + 4 * c);
        G.r3 = *(const uint2*)(NCb + (size_t)I.r3 * 128 + 4 * c);
        G.s0 = *(const uint2*)(NCb + (size_t)I.s0 * 128 + 64 + 4 * c);
        G.s1 = *(const uint2*)(NCb + (size_t)I.s1 * 128 + 64 + 4 * c);
        G.s2 = *(const uint2*)(NCb + (size_t)I.s2 * 128 + 64 + 4 * c);
        G.s3 = *(const uint2*)(NCb + (size_t)I.s3 * 128 + 64 + 4 * c);
        return G;
    };
    auto addg = [&](floatx4 v, uint2 r, uint2 s) {
        v[0] += __uint_as_float(r.x << 16) + __uint_as_float(s.x << 16);
        v[1] += __uint_as_float(r.x & 0xFFFF0000u) + __uint_as_float(s.x & 0xFFFF0000u);
        v[2] += __uint_as_float(r.y << 16) + __uint_as_float(s.y << 16);
        v[3] += __uint_as_float(r.y & 0xFFFF0000u) + __uint_as_float(s.y & 0xFFFF0000u);
        return v;
    };

    auto compute_store = [&](char* buf, int b0, const GathRegs& G) {
        const int s = (e16 & 7);
        floatx4 a0lo = *(const floatx4*)(buf + e16 * 256 + ((2 * g + 0) ^ s) * 16);
        floatx4 a0hi = *(const floatx4*)(buf + e16 * 256 + ((2 * g + 1) ^ s) * 16);
        floatx4 a1lo = *(const floatx4*)(buf + e16 * 256 + ((2 * g + 8) ^ s) * 16);
        floatx4 a1hi = *(const floatx4*)(buf + e16 * 256 + ((2 * g + 9) ^ s) * 16);
        short8 A0 = cvt2(a0lo, a0hi);
        short8 A1 = cvt2(a1lo, a1hi);

        floatx4 acc0 = {0,0,0,0}, acc1 = {0,0,0,0}, acc2 = {0,0,0,0}, acc3 = {0,0,0,0};
        acc0 = __builtin_amdgcn_mfma_f32_16x16x32_bf16(Bf[0], A0, acc0, 0, 0, 0);
        acc1 = __builtin_amdgcn_mfma_f32_16x16x32_bf16(Bf[1], A0, acc1, 0, 0, 0);
        acc2 = __builtin_amdgcn_mfma_f32_16x16x32_bf16(Bf[2], A0, acc2, 0, 0, 0);
        acc3 = __builtin_amdgcn_mfma_f32_16x16x32_bf16(Bf[3], A0, acc3, 0, 0, 0);
        acc0 = __builtin_amdgcn_mfma_f32_16x16x32_bf16(Bf[4], A1, acc0, 0, 0, 0);
        acc1 = __builtin_amdgcn_mfma_f32_16x16x32_bf16(Bf[5], A1, acc1, 0, 0, 0);
        acc2 = __builtin_amdgcn_mfma_f32_16x16x32_bf16(Bf[6], A1, acc2, 0, 0, 0);
        acc3 = __builtin_amdgcn_mfma_f32_16x16x32_bf16(Bf[7], A1, acc3, 0, 0, 0);

#pragma unroll
        for (int j = 0; j < 4; ++j) {
            floatx4 v = (floatx4){acc0[j], acc1[j], acc2[j], acc3[j]};
            *(floatx4*)(buf + e16 * 256 + ((4 * g + j) ^ s) * 16) = v;
        }

#pragma unroll
        for (int i = 0; i < 4; ++i) {
            int r = 4 * i + lr;
            floatx4 v = *(const floatx4*)(buf + r * 256 + (c ^ (r & 7)) * 16);
            v += gc4;
            if (i == 0) v = addg(v, G.r0, G.s0);
            else if (i == 1) v = addg(v, G.r1, G.s1);
            else if (i == 2) v = addg(v, G.r2, G.s2);
            else v = addg(v, G.r3, G.s3);
            int row = b0 + r;
            if (row < E)
                __builtin_nontemporal_store(v, (floatx4*)(out + (size_t)row * D_OUT + 4 * c));
        }
    };

    // ---- prologue: edges 2-deep, gathers 3-deep, idx 4 ahead ----
    IdxRegs I0 = load_idx(TBASE(0));
    IdxRegs I1 = (T > 1) ? load_idx(TBASE(1)) : I0;
    IdxRegs I2 = (T > 2) ? load_idx(TBASE(2)) : I1;
    IdxRegs In = (T > 3) ? load_idx(TBASE(3)) : I2;   // idx for tile k+3

    {
        EdgeRegs E0 = load_edges(TBASE(0));
        stage_edges(&lds[wave][0][0], E0);
    }
    GathRegs G0 = load_gath(I0);                      // tile k
    EdgeRegs E1;                                      // edges tile k+1 (regs)
    GathRegs G1, G2;                                  // gathers k+1, k+2
    if (T > 1) {
        E1 = load_edges(TBASE(1));
        G1 = load_gath(I1);
    }
    if (T > 2) G2 = load_gath(I2);
    int cur = 0;

#pragma unroll 1
    for (int k = 0; k < T; ++k) {
        // issue tile k+2 edges and tile k+3 gathers (arrive 2+ phases later)
        EdgeRegs E2 = E1;
        if (k + 2 < T) E2 = load_edges(TBASE(k + 2));
        GathRegs G3 = G2;
        if (k + 3 < T) G3 = load_gath(In);
        IdxRegs I4 = In;
        if (k + 4 < T) I4 = load_idx(TBASE(k + 4));

        compute_store(&lds[wave][cur][0], TBASE(k), G0);

        if (k + 1 < T) stage_edges(&lds[wave][cur ^ 1][0], E1);

        E1 = E2; G0 = G1; G1 = G2; G2 = G3; In = I4; cur ^= 1;
    }
#undef TBASE
}

// ---------------- Fallback path (round-1 kernel) if ws too small ----------------

#define NKSTEP 6
#define NFRAG  (NKSTEP * 4)
#define ITERS 4

__global__ void pack_kernel(const float* __restrict__ W, const float* __restrict__ b,
                            const float* __restrict__ g,
                            unsigned short* __restrict__ wp, float* __restrict__ gc) {
    int tid = blockIdx.x * 256 + threadIdx.x;
    if (tid < NFRAG * 64) {
        int lane = tid & 63;
        int ct = (tid >> 6) & 3;
        int kstep = tid >> 8;
        int kbase = kstep * 32 + (lane >> 4) * 8;
        int col = ct * 16 + (lane & 15);
        short8 sv;
#pragma unroll
        for (int j = 0; j < 8; ++j)
            sv[j] = (short)f2bf(W[(size_t)(kbase + j) * D_OUT + col]);
        *(short8*)(wp + (size_t)tid * 8) = sv;
    } else if (tid < NFRAG * 64 + 64) {
        int col = tid - NFRAG * 64;
        float acc = b[col];
#pragma unroll
        for (int k = 0; k < 32; ++k)
            acc += g[k] * W[(size_t)(192 + k) * D_OUT + col];
        gc[col] = acc;
    }
}

__global__ __launch_bounds__(256) void edge_kernel(
    const float* __restrict__ edges, const float* __restrict__ nodes,
    const int* __restrict__ recv, const int* __restrict__ send,
    const unsigned short* __restrict__ wp, const float* __restrict__ gc,
    float* __restrict__ out, int E) {

    const int lane = threadIdx.x & 63;
    const int wave = threadIdx.x >> 6;

    short8 Bf[NFRAG];
#pragma unroll
    for (int fi = 0; fi < NFRAG; ++fi)
        Bf[fi] = *(const short8*)(wp + ((size_t)fi * 64 + lane) * 8);

    const int colbase = lane & 15;
    float gv[4];
#pragma unroll
    for (int ct = 0; ct < 4; ++ct) gv[ct] = gc[ct * 16 + colbase];

    const int koff = (lane >> 4) * 8;

    for (int it = 0; it < ITERS; ++it) {
        int ebase = (blockIdx.x * ITERS + it) * 64 + wave * 16;
        if (ebase >= E) break;

        int ea = ebase + (lane & 15);
        if (ea >= E) ea = E - 1;
        int ri = recv[ea];
        int si = send[ea];

        const float* pe = edges + (size_t)ea * D_NODE + koff;
        const float* pr = nodes + (size_t)ri * D_NODE + koff;
        const float* ps = nodes + (size_t)si * D_NODE + koff;

        short8 A[NKSTEP];
        A[0] = load_cvt(pe);
        A[1] = load_cvt(pe + 32);
        A[2] = load_cvt(pr);
        A[3] = load_cvt(pr + 32);
        A[4] = load_cvt(ps);
        A[5] = load_cvt(ps + 32);

        floatx4 acc[4];
#pragma unroll
        for (int ct = 0; ct < 4; ++ct)
            acc[ct] = (floatx4){gv[ct], gv[ct], gv[ct], gv[ct]};

#pragma unroll
        for (int ks = 0; ks < NKSTEP; ++ks) {
#pragma unroll
            for (int ct = 0; ct < 4; ++ct)
                acc[ct] = __builtin_amdgcn_mfma_f32_16x16x32_bf16(
                    A[ks], Bf[ks * 4 + ct], acc[ct], 0, 0, 0);
        }

        int crow = ebase + (lane >> 4) * 4;
#pragma unroll
        for (int ct = 0; ct < 4; ++ct) {
#pragma unroll
            for (int r4 = 0; r4 < 4; ++r4) {
                int row = crow + r4;
                if (row < E)
                    out[(size_t)row * D_OUT + ct * 16 + colbase] = acc[ct][r4];
            }
        }
    }
}

extern "C" void kernel_launch(void* const* d_in, const int* in_sizes, int n_in,
                              void* d_out, int out_size, void* d_ws, size_t ws_size,
                              hipStream_t stream) {
    const float* edges = (const float*)d_in[0];
    const float* nodes = (const float*)d_in[1];
    const float* glob  = (const float*)d_in[2];
    const int*   recv  = (const int*)d_in[3];
    const int*   send  = (const int*)d_in[4];
    const float* W     = (const float*)d_in[5];
    const float* b     = (const float*)d_in[6];
    float* out = (float*)d_out;

    int E  = in_sizes[0] / D_NODE;
    int Nn = in_sizes[1] / D_NODE;

    size_t nc_bytes  = (size_t)Nn * 128 * 2;   // bf16 NC
    size_t wpe_bytes = 512 * 8 * 2;
    size_t wpn_bytes = 1024 * 8 * 2;
    size_t need = nc_bytes + wpe_bytes + wpn_bytes + 256;

    if (ws_size >= need) {
        unsigned short* NCb = (unsigned short*)d_ws;
        unsigned short* wpe = (unsigned short*)((char*)d_ws + nc_bytes);
        unsigned short* wpn = (unsigned short*)((char*)d_ws + nc_bytes + wpe_bytes);
        float* gc = (float*)((char*)d_ws + nc_bytes + wpe_bytes + wpn_bytes);

        pack2_kernel<<<7, 256, 0, stream>>>(W, b, glob, wpe, wpn, gc);
        node3_kernel<<<(Nn + 63) / 64, 256, 0, stream>>>(nodes, wpn, NCb, Nn);

        int NT = (E + 63) / 64;
        int grid = (NT < 2500) ? NT : 2500;
        int T = (NT + grid - 1) / grid;
        edge10_kernel<<<grid, 256, 0, stream>>>(edges, recv, send, wpe, NCb, gc, out, E, T);
    } else {
        unsigned short* wp = (unsigned short*)d_ws;
        float* gc = (float*)((char*)d_ws + NFRAG * 64 * 8 * 2);
        pack_kernel<<<7, 256, 0, stream>>>(W, b, glob, wp, gc);
        int nblk = (E + ITERS * 64 - 1) / (ITERS * 64);
        edge_kernel<<<nblk, 256, 0, stream>>>(edges, nodes, recv, send, wp, gc, out, E);
    }
}